// Round 15
// baseline (117.162 us; speedup 1.0000x reference)
//
#include <hip/hip_runtime.h>
#include <hip/hip_bf16.h>
#include <cstdint>
#include <math.h>

#define B_DIM 32
#define T_DIM 1000
#define D_DIM 768
#define V_DIM 31
#define L_DIM 200
#define S_DIM 401      // 2L+1 CTC states
#define SP 8           // states per lane (64*8 = 512 >= 401; uniform parity)
#define S_PAD 512
#define VSTRIDE 32     // padded prob-row stride: 32 floats = 128 B

typedef __bf16 bf16x8 __attribute__((ext_vector_type(8)));
typedef float  f32x16 __attribute__((ext_vector_type(16)));
typedef __attribute__((address_space(3))) float lds_float;

#define SB() __builtin_amdgcn_sched_barrier(0)

// Wave-wide shift-up-by-1 via DPP WAVE_SHR1 (0x138): pure VALU. Lane 0 -> 0.
__device__ __forceinline__ float shup1_f(float x) {
    int r = __builtin_amdgcn_update_dpp(0, __float_as_int(x), 0x138, 0xF, 0xF, true);
    return __int_as_float(r);
}
__device__ __forceinline__ int shup1_i(int x) {
    return __builtin_amdgcn_update_dpp(0, x, 0x138, 0xF, 0xF, true);
}

// ---------------------------------------------------------------------------
// Kernel 0: one-time W f32 -> bf16 (hoists B-side cvt out of the head).
// grid 93 x 256 = 23808 = 31*768 exactly.
// ---------------------------------------------------------------------------
__global__ void wcvt_kernel(const float* __restrict__ W, __bf16* __restrict__ Wb)
{
    const int i = blockIdx.x * 256 + threadIdx.x;
    Wb[i] = (__bf16)W[i];
}

// ---------------------------------------------------------------------------
// Kernel 1: logits = pred @ W^T + b via MFMA bf16, probs = softmax -> ws.
// B-fragments load pre-converted bf16 W directly (1 dwordx4 per MFMA).
// ---------------------------------------------------------------------------
__global__ __launch_bounds__(256) void head_softmax_kernel(
    const float* __restrict__ pred,
    const __bf16* __restrict__ Wb,
    const float* __restrict__ bias,
    float* __restrict__ probs)
{
    __shared__ float red[3][64][16];   // waves 1..3 partial C tiles (12 KB)
    __shared__ float sm2[32][33];      // transpose pad 33 -> conflict-free
    const int tid  = threadIdx.x;
    const int lane = tid & 63;
    const int w    = __builtin_amdgcn_readfirstlane(tid >> 6);  // K segment
    const int col  = lane & 31;
    const int h    = lane >> 5;
    const int row  = blockIdx.x * 32 + col;     // grid = 1000 exactly
    const int vc   = (col < V_DIM) ? col : (V_DIM - 1);  // clamp pad col

    const float*  pA = pred + (size_t)row * D_DIM + w * 192 + 8 * h;
    const __bf16* pB = Wb + (size_t)vc * D_DIM + w * 192 + 8 * h;

    f32x16 acc;
#pragma unroll
    for (int i = 0; i < 16; ++i) acc[i] = 0.f;

#pragma unroll
    for (int kt = 0; kt < 12; ++kt) {
        const float4 a0 = *reinterpret_cast<const float4*>(pA + kt * 16);
        const float4 a1 = *reinterpret_cast<const float4*>(pA + kt * 16 + 4);
        const bf16x8 bfr = *reinterpret_cast<const bf16x8*>(pB + kt * 16);
        bf16x8 af;
        af[0] = (__bf16)a0.x; af[1] = (__bf16)a0.y;
        af[2] = (__bf16)a0.z; af[3] = (__bf16)a0.w;
        af[4] = (__bf16)a1.x; af[5] = (__bf16)a1.y;
        af[6] = (__bf16)a1.z; af[7] = (__bf16)a1.w;
        acc = __builtin_amdgcn_mfma_f32_32x32x16_bf16(af, bfr, acc, 0, 0, 0);
    }

    if (w > 0) {
#pragma unroll
        for (int q = 0; q < 4; ++q)
            *reinterpret_cast<float4*>(&red[w - 1][lane][q * 4]) =
                make_float4(acc[q * 4], acc[q * 4 + 1], acc[q * 4 + 2], acc[q * 4 + 3]);
    }
    __syncthreads();
    if (w == 0) {
#pragma unroll
        for (int i = 0; i < 16; ++i)
            acc[i] += red[0][lane][i] + red[1][lane][i] + red[2][lane][i];
#pragma unroll
        for (int r = 0; r < 16; ++r) {
            const int rl = (r & 3) + 8 * (r >> 2) + 4 * h;
            sm2[rl][col] = acc[r];
        }
        if (lane < 32) {
            float lg[V_DIM];
            float m = -1e30f;
#pragma unroll
            for (int v = 0; v < V_DIM; ++v) {
                lg[v] = sm2[lane][v] + bias[v];
                m = fmaxf(m, lg[v]);
            }
            float e[32];
            float s = 0.f;
#pragma unroll
            for (int v = 0; v < V_DIM; ++v) { e[v] = __expf(lg[v] - m); s += e[v]; }
            const float inv = 1.0f / s;
#pragma unroll
            for (int v = 0; v < V_DIM; ++v) e[v] *= inv;
            e[31] = 0.f;
            float* op = probs + (size_t)(blockIdx.x * 32 + lane) * VSTRIDE;
#pragma unroll
            for (int q = 0; q < 8; ++q)
                *reinterpret_cast<float4*>(op + q * 4) =
                    *reinterpret_cast<float4*>(&e[q * 4]);
        }
    }
}

// --- inline-asm gather: 4 label reads + 1 blank-broadcast, literal offset --
#define DS1(dst, vaddr, off) \
    asm volatile("ds_read_b32 %0, %1 offset:" #off : "=v"(dst) : "v"(vaddr))
#define RD5(G, off) do { \
    DS1(G[0], va[0], off); DS1(G[1], va[1], off); DS1(G[2], va[2], off); \
    DS1(G[3], va[3], off); DS1(G[4], va[4], off); } while (0)
// counted wait: 10 outstanding = the two just-issued groups; older retired.
#define W10() do { \
    asm volatile("s_waitcnt lgkmcnt(10)" ::: "memory"); \
    __builtin_amdgcn_sched_barrier(0); } while (0)

// ---------------------------------------------------------------------------
// Kernel 2: CTC forward recursion, linear domain, pow2 renorm every 2 steps.
// All pow2 scaling via exponent BIT-MATH (no ldexpf/frexpf -> no OCML
// wrapper code): exact, full-rate v_mul/v_bfe only.
// ---------------------------------------------------------------------------
__global__ __launch_bounds__(64, 1) void ctc_alpha_kernel(
    const float* __restrict__ probs,
    const int* __restrict__ targets,
    const int* __restrict__ in_lens,
    const int* __restrict__ tgt_lens,
    float* __restrict__ out_nll)
{
    __shared__ float lbuf[3][16][VSTRIDE];   // 6 KB ring (3 chunks x 16 rows)
    __shared__ float sal[S_PAD];

    const int b    = blockIdx.x;
    const int lane = threadIdx.x;
    const int Tin  = in_lens[b];
    const int tl   = tgt_lens[b];
    const int* tgt = targets + b * L_DIM;
    const float* __restrict__ prow = probs + (size_t)b * T_DIM * VSTRIDE;

    // Per-lane: 4 odd-state labels (contiguous tgt[4l..4l+3], clamped) + skip
    // masks. Pad states (>=401) are inert: transitions only flow upward in s.
    int   loff[4];
    float m2o[4];
#pragma unroll
    for (int j = 0; j < 4; ++j) {
        int k = 4 * lane + j;
        if (k > L_DIM - 1) k = L_DIM - 1;
        const int lab = tgt[k];
        loff[j] = lab;
        const int s   = 8 * lane + 2 * j + 1;
        const int km1 = (k > 0) ? k - 1 : 0;
        m2o[j] = (s >= 3 && lab != tgt[km1]) ? 1.f : 0.f;
    }

    // LDS byte addresses for the asm gathers (loop-invariant VGPRs).
    const uint32_t base = (uint32_t)(uintptr_t)(lds_float*)&lbuf[0][0][0];
    uint32_t va[5];
#pragma unroll
    for (int j = 0; j < 4; ++j) va[j] = base + (uint32_t)(loff[j] * 4);
    va[4] = base;                              // blank (broadcast) address

    // t=0 init
    float a[SP];
#pragma unroll
    for (int i = 0; i < SP; ++i) a[i] = 0.f;
    if (lane == 0) {
        a[0] = prow[0];
        a[1] = prow[loff[0]];
    }
    int   z2 = 0;
    const float fz = (lane == 0) ? 0.f : 1.0f;   // lane-0 inflow killer
    float f  = fz;

    auto ISSUE = [&](int buf, int tbase) {
#pragma unroll
        for (int i = 0; i < 8; ++i) {
            int rowb = tbase + 2 * i;
            if (rowb > T_DIM - 2) rowb = T_DIM - 2;   // clamp, stays in-bounds
            const float* src = prow + (size_t)rowb * VSTRIDE + lane;
            float* dst = &lbuf[buf][2 * i][0];        // wave-uniform base
            __builtin_amdgcn_global_load_lds(
                (const __attribute__((address_space(1))) void*)src,
                (__attribute__((address_space(3))) void*)dst, 4, 0, 0);
        }
    };

    float GA[5], GB[5], GC[5], GD[5];
    // plain C++ gather (tail only)
    auto RDC = [&](const float* bp, int row, float (&G)[5]) {
#pragma unroll
        for (int j = 0; j < 4; ++j) G[j] = bp[row * VSTRIDE + loff[j]];
        G[4] = bp[row * VSTRIDE];
    };

    // G[0..3] = odd-state label probs, G[4] = blank prob (all lanes equal).
    auto STEP = [&](const float (&G)[5]) {
        const float a7p = shup1_f(a[7]);        // prev-lane state 8l-1
        const float am1 = a7p * f;              // f==0 on lane 0
        float nw[SP];
        nw[0] = (a[0] + am1)                    * G[4];
        nw[1] = (a[1] + a[0] + m2o[0] * am1)    * G[0];
        nw[2] = (a[2] + a[1])                   * G[4];
        nw[3] = (a[3] + a[2] + m2o[1] * a[1])   * G[1];
        nw[4] = (a[4] + a[3])                   * G[4];
        nw[5] = (a[5] + a[4] + m2o[2] * a[3])   * G[2];
        nw[6] = (a[6] + a[5])                   * G[4];
        nw[7] = (a[7] + a[6] + m2o[3] * a[5])   * G[3];
#pragma unroll
        for (int i = 0; i < SP; ++i) a[i] = nw[i];
    };

    // Pow2 renorm via bit-math only (exact; FTZ-consistent with ldexp path):
    // e = floor-exp with mant in [0.5,1); s = 2^-e; f = fz * 2^dz.
    auto RENORM = [&]() {
        const float mA = fmaxf(fmaxf(a[0], a[1]), fmaxf(a[2], a[3]));
        const float mB = fmaxf(fmaxf(a[4], a[5]), fmaxf(a[6], a[7]));
        const float mx = fmaxf(mA, mB);
        const int e  = (int)((__float_as_uint(mx) >> 23) & 0xFFu) - 126;
        const int zc = z2 + e;
        const int zp = shup1_i(zc);              // lane0 -> 0 (never used there)
        z2 = (mx > 0.f) ? zc : zp;               // empty lanes adopt neighbor
        const float s = __uint_as_float((uint32_t)(127 - e) << 23);  // 2^-e
#pragma unroll
        for (int i = 0; i < SP; ++i) a[i] *= s;
        int dz = zp - z2;
        dz = (dz > 126) ? 126 : ((dz < -126) ? -126 : dz);  // -> med3
        f = fz * __uint_as_float((uint32_t)(127 + dz) << 23);  // lane0 -> 0
    };

    ISSUE(0, 1);            // chunk 0: rows 1..16
    ISSUE(1, 17);           // chunk 1: rows 17..32
    asm volatile("s_waitcnt vmcnt(8)" ::: "memory");  // chunk 0 landed
    RD5(GA, 0);             // row 0 of chunk 0
    RD5(GB, 128);           // row 1 of chunk 0

    int tb = 1;
    int cur = 0;
    while (tb + 16 <= Tin) {
        const int nx = (cur + 1 == 3) ? 0 : cur + 1;
        const int n2 = (nx + 1 == 3) ? 0 : nx + 1;
        // 14 in-chunk steps: read row j+2, wait counted, compute row j
        RD5(GC, 256);  W10(); STEP(GA);
        RD5(GD, 384);  W10(); STEP(GB); RENORM();
        RD5(GA, 512);  W10(); STEP(GC);
        RD5(GB, 640);  W10(); STEP(GD); RENORM();
        RD5(GC, 768);  W10(); STEP(GA);
        RD5(GD, 896);  W10(); STEP(GB); RENORM();
        RD5(GA, 1024); W10(); STEP(GC);
        RD5(GB, 1152); W10(); STEP(GD); RENORM();
        RD5(GC, 1280); W10(); STEP(GA);
        RD5(GD, 1408); W10(); STEP(GB); RENORM();
        RD5(GA, 1536); W10(); STEP(GC);
        RD5(GB, 1664); W10(); STEP(GD); RENORM();
        RD5(GC, 1792); W10(); STEP(GA);
        RD5(GD, 1920); W10(); STEP(GB); RENORM();
        // advance va ring to next chunk (off critical path)
#pragma unroll
        for (int i = 0; i < 5; ++i) {
            uint32_t o = va[i] + 2048u - base;
            if (o >= 6144u) o -= 6144u;
            va[i] = base + o;
        }
        ISSUE(n2, tb + 32);                                // refill oldest
        asm volatile("s_waitcnt vmcnt(8)" ::: "memory");   // next chunk landed
        RD5(GA, 0);    W10(); STEP(GC);                    // row 14
        RD5(GB, 128);  W10(); STEP(GD); RENORM();          // row 15
        tb += 16;
        cur = nx;
    }

    // drain asm reads once; tail (<16 steps) in plain C++
    asm volatile("s_waitcnt lgkmcnt(0)" ::: "memory");
    SB();
    const int rem = Tin - tb;
    {
        const float* Lb = &lbuf[cur][0][0];
        if (rem >  0) { RDC(Lb,  2, GC); STEP(GA); }
        if (rem >  1) { RDC(Lb,  3, GD); STEP(GB); RENORM(); }
        if (rem >  2) { RDC(Lb,  4, GA); STEP(GC); }
        if (rem >  3) { RDC(Lb,  5, GB); STEP(GD); RENORM(); }
        if (rem >  4) { RDC(Lb,  6, GC); STEP(GA); }
        if (rem >  5) { RDC(Lb,  7, GD); STEP(GB); RENORM(); }
        if (rem >  6) { RDC(Lb,  8, GA); STEP(GC); }
        if (rem >  7) { RDC(Lb,  9, GB); STEP(GD); RENORM(); }
        if (rem >  8) { RDC(Lb, 10, GC); STEP(GA); }
        if (rem >  9) { RDC(Lb, 11, GD); STEP(GB); RENORM(); }
        if (rem > 10) { RDC(Lb, 12, GA); STEP(GC); }
        if (rem > 11) { RDC(Lb, 13, GB); STEP(GD); RENORM(); }
        if (rem > 12) { RDC(Lb, 14, GC); STEP(GA); }
        if (rem > 13) { RDC(Lb, 15, GB); STEP(GD); RENORM(); }
        if (rem > 14) { STEP(GC); RENORM(); }
    }

    // absolute log-alpha: log(a) + z2*ln2
    const float zln2 = (float)z2 * 0.69314718055994530942f;
#pragma unroll
    for (int i = 0; i < SP; ++i) sal[lane * SP + i] = __logf(a[i]) + zln2;
    __syncthreads();
    if (lane == 0) {
        const float a0 = sal[2 * tl - 1];
        const float a1 = sal[2 * tl];
        const float m  = fmaxf(a0, a1);
        float nll = -(m + __logf(__expf(a0 - m) + __expf(a1 - m)));
        if (!(nll < 1e29f)) nll = 0.f;           // zero_infinity (inf/NaN too)
        out_nll[b] = nll / (float)tl;
    }
}

// ---------------------------------------------------------------------------
// Kernel 3: deterministic mean over B
// ---------------------------------------------------------------------------
__global__ void finalize_kernel(const float* __restrict__ nll, float* __restrict__ out)
{
    if (threadIdx.x == 0 && blockIdx.x == 0) {
        float s = 0.f;
        for (int i = 0; i < B_DIM; ++i) s += nll[i];
        out[0] = s * (1.0f / (float)B_DIM);
    }
}

extern "C" void kernel_launch(void* const* d_in, const int* in_sizes, int n_in,
                              void* d_out, int out_size, void* d_ws, size_t ws_size,
                              hipStream_t stream)
{
    const float* pred     = (const float*)d_in[0];
    const int*   targets  = (const int*)d_in[1];
    const int*   in_lens  = (const int*)d_in[2];
    const int*   tgt_lens = (const int*)d_in[3];
    const float* W        = (const float*)d_in[4];
    const float* bias     = (const float*)d_in[5];

    float* probs = (float*)d_ws;                                  // 32*1000*32 f32 = 4.1 MB
    float* nll   = probs + (size_t)B_DIM * T_DIM * VSTRIDE;       // 32 f32
    __bf16* Wb   = (__bf16*)(nll + B_DIM);                        // 31*768 bf16 = 47.6 KB
    float* out   = (float*)d_out;

    wcvt_kernel<<<(V_DIM * D_DIM) / 256, 256, 0, stream>>>(W, Wb);
    head_softmax_kernel<<<(B_DIM * T_DIM) / 32, 256, 0, stream>>>(pred, Wb, bias, probs);
    ctc_alpha_kernel<<<B_DIM, 64, 0, stream>>>(probs, targets, in_lens, tgt_lens, nll);
    finalize_kernel<<<1, 64, 0, stream>>>(nll, out);
}

// Round 16
// 97.609 us; speedup vs baseline: 1.2003x; 1.2003x over previous
//
#include <hip/hip_runtime.h>
#include <hip/hip_bf16.h>
#include <cstdint>
#include <math.h>

#define B_DIM 32
#define T_DIM 1000
#define D_DIM 768
#define V_DIM 31
#define L_DIM 200
#define S_DIM 401      // 2L+1 CTC states
#define S_PAD 512      // 2 waves x 64 lanes x 4 states
#define VSTRIDE 32     // padded prob-row stride: 32 floats = 128 B

typedef __bf16 bf16x8 __attribute__((ext_vector_type(8)));
typedef float  f32x16 __attribute__((ext_vector_type(16)));
typedef float  f32x2  __attribute__((ext_vector_type(2)));
typedef __attribute__((address_space(3))) float lds_float;

#define SB() __builtin_amdgcn_sched_barrier(0)

// Wave-wide shift-up-by-1 via DPP WAVE_SHR1 (0x138): pure VALU. Lane 0 -> 0.
__device__ __forceinline__ float shup1_f(float x) {
    int r = __builtin_amdgcn_update_dpp(0, __float_as_int(x), 0x138, 0xF, 0xF, true);
    return __int_as_float(r);
}
__device__ __forceinline__ int shup1_i(int x) {
    return __builtin_amdgcn_update_dpp(0, x, 0x138, 0xF, 0xF, true);
}

// ---------------------------------------------------------------------------
// Kernel 1: logits = pred @ W^T + b via MFMA bf16, probs = softmax -> ws.
// (r14 version: in-kernel cvt, ~29 us.)
// ---------------------------------------------------------------------------
__global__ __launch_bounds__(256) void head_softmax_kernel(
    const float* __restrict__ pred,
    const float* __restrict__ W,
    const float* __restrict__ bias,
    float* __restrict__ probs)
{
    __shared__ float red[3][64][16];
    __shared__ float sm2[32][33];
    const int tid  = threadIdx.x;
    const int lane = tid & 63;
    const int w    = __builtin_amdgcn_readfirstlane(tid >> 6);
    const int col  = lane & 31;
    const int h    = lane >> 5;
    const int row  = blockIdx.x * 32 + col;
    const int vc   = (col < V_DIM) ? col : (V_DIM - 1);

    const float* pA = pred + (size_t)row * D_DIM + w * 192 + 8 * h;
    const float* pB = W + (size_t)vc * D_DIM + w * 192 + 8 * h;

    f32x16 acc;
#pragma unroll
    for (int i = 0; i < 16; ++i) acc[i] = 0.f;

#pragma unroll
    for (int kt = 0; kt < 12; ++kt) {
        const float4 a0 = *reinterpret_cast<const float4*>(pA + kt * 16);
        const float4 a1 = *reinterpret_cast<const float4*>(pA + kt * 16 + 4);
        const float4 b0 = *reinterpret_cast<const float4*>(pB + kt * 16);
        const float4 b1 = *reinterpret_cast<const float4*>(pB + kt * 16 + 4);
        bf16x8 af, bfr;
        af[0] = (__bf16)a0.x; af[1] = (__bf16)a0.y;
        af[2] = (__bf16)a0.z; af[3] = (__bf16)a0.w;
        af[4] = (__bf16)a1.x; af[5] = (__bf16)a1.y;
        af[6] = (__bf16)a1.z; af[7] = (__bf16)a1.w;
        bfr[0] = (__bf16)b0.x; bfr[1] = (__bf16)b0.y;
        bfr[2] = (__bf16)b0.z; bfr[3] = (__bf16)b0.w;
        bfr[4] = (__bf16)b1.x; bfr[5] = (__bf16)b1.y;
        bfr[6] = (__bf16)b1.z; bfr[7] = (__bf16)b1.w;
        acc = __builtin_amdgcn_mfma_f32_32x32x16_bf16(af, bfr, acc, 0, 0, 0);
    }

    if (w > 0) {
#pragma unroll
        for (int q = 0; q < 4; ++q)
            *reinterpret_cast<float4*>(&red[w - 1][lane][q * 4]) =
                make_float4(acc[q * 4], acc[q * 4 + 1], acc[q * 4 + 2], acc[q * 4 + 3]);
    }
    __syncthreads();
    if (w == 0) {
#pragma unroll
        for (int i = 0; i < 16; ++i)
            acc[i] += red[0][lane][i] + red[1][lane][i] + red[2][lane][i];
#pragma unroll
        for (int r = 0; r < 16; ++r) {
            const int rl = (r & 3) + 8 * (r >> 2) + 4 * h;
            sm2[rl][col] = acc[r];
        }
        if (lane < 32) {
            float lg[V_DIM];
            float m = -1e30f;
#pragma unroll
            for (int v = 0; v < V_DIM; ++v) {
                lg[v] = sm2[lane][v] + bias[v];
                m = fmaxf(m, lg[v]);
            }
            float e[32];
            float s = 0.f;
#pragma unroll
            for (int v = 0; v < V_DIM; ++v) { e[v] = __expf(lg[v] - m); s += e[v]; }
            const float inv = 1.0f / s;
#pragma unroll
            for (int v = 0; v < V_DIM; ++v) e[v] *= inv;
            e[31] = 0.f;
            float* op = probs + (size_t)(blockIdx.x * 32 + lane) * VSTRIDE;
#pragma unroll
            for (int q = 0; q < 8; ++q)
                *reinterpret_cast<float4*>(op + q * 4) =
                    *reinterpret_cast<float4*>(&e[q * 4]);
        }
    }
}

// --- asm helpers (counted waits; rule #18: sched_barrier after lgkmcnt) ----
#define WTn(n) do { asm volatile("s_waitcnt lgkmcnt(" #n ")" ::: "memory"); SB(); } while (0)
#define VM8()  asm volatile("s_waitcnt vmcnt(8)" ::: "memory")
#define BARR() do { asm volatile("s_waitcnt lgkmcnt(0)" ::: "memory"); SB(); \
                    asm volatile("s_barrier" ::: "memory"); SB(); } while (0)
#define RD3(G, off) do { \
    asm volatile("ds_read_b32 %0, %1 offset:" #off : "=v"(G[0]) : "v"(va[0])); \
    asm volatile("ds_read_b32 %0, %1 offset:" #off : "=v"(G[1]) : "v"(va[1])); \
    asm volatile("ds_read_b32 %0, %1 offset:" #off : "=v"(G[2]) : "v"(va[2])); } while (0)
#define RDE(E, base, off) \
    asm volatile("ds_read_b64 %0, %1 offset:" #off : "=v"(E) : "v"(base))
#define WB(o0, o1) \
    asm volatile("ds_write2_b32 %0, %1, %2 offset0:" #o0 " offset1:" #o1 \
                 :: "v"(wcur), "v"(a[3]), "v"(z2) : "memory")

// ---------------------------------------------------------------------------
// Kernel 2: CTC forward recursion, linear domain, pow2 renorm every 2 steps.
// TWO waves per batch, skewed pipeline: wave0 = states 0..255 (leads by one
// 16-step chunk, DMA-stages probs, writes boundary (a255,z2) per step);
// wave1 = states 256..511 (trails one chunk, consumes boundary entries with
// exact per-step pow2 rescale). One raw s_barrier per chunk (no vmcnt drain).
// ---------------------------------------------------------------------------
__global__ __launch_bounds__(128, 1) void ctc_alpha_kernel(
    const float* __restrict__ probs,
    const int* __restrict__ targets,
    const int* __restrict__ in_lens,
    const int* __restrict__ tgt_lens,
    float* __restrict__ out_nll)
{
    __shared__ float lbuf[4][16][VSTRIDE];          // 8 KB, slot = chunk%4
    __shared__ __align__(8) float bndb[3][16][2];   // boundary ring (a255, zbits)
    __shared__ float trash[256];                    // decoy for lane!=63 writes
    __shared__ float sal[S_PAD];

    const int b    = blockIdx.x;
    const int tid  = threadIdx.x;
    const int lane = tid & 63;
    const int w    = __builtin_amdgcn_readfirstlane(tid >> 6);
    const int Tin  = in_lens[b];
    const int tl   = tgt_lens[b];
    const int* tgt = targets + b * L_DIM;
    const float* __restrict__ prow = probs + (size_t)b * T_DIM * VSTRIDE;

    const int NS = Tin - 1;        // steps t = 1..Tin-1
    const int F  = NS >> 4;        // full chunks
    const int R  = NS & 15;        // remainder steps

    // per-lane labels (2 odd states) + skip masks; pad states inert
    int k0 = (w ? 128 : 0) + 2 * lane;
    int k1 = k0 + 1;
    if (k0 > L_DIM - 1) k0 = L_DIM - 1;
    if (k1 > L_DIM - 1) k1 = L_DIM - 1;
    const int loff0 = tgt[k0];
    const int loff1 = tgt[k1];
    const int k0m   = (k0 > 0) ? k0 - 1 : 0;
    const float m20 = (w == 0 && lane == 0) ? 0.f : ((loff0 != tgt[k0m]) ? 1.f : 0.f);
    const float m21 = (loff1 != tgt[k1 - 1]) ? 1.f : 0.f;

    const uint32_t lb_base  = (uint32_t)(uintptr_t)(lds_float*)&lbuf[0][0][0];
    const uint32_t bnd_base = (uint32_t)(uintptr_t)(lds_float*)&bndb[0][0][0];
    const uint32_t tr_base  = (uint32_t)(uintptr_t)(lds_float*)&trash[0];

    float a[4] = {0.f, 0.f, 0.f, 0.f};
    int   z2 = 0;
    const float fz = (lane == 0) ? 0.f : 1.0f;
    float f = fz;

    uint32_t va[3];
    va[0] = lb_base + (uint32_t)(loff0 * 4);
    va[1] = lb_base + (uint32_t)(loff1 * 4);
    va[2] = lb_base;

    float GA[3], GB[3], GC[3], GD[3];

    if (w == 0) {
        // ============================ WAVE 0 ============================
        if (lane == 0) {            // t=0 init: states 0,1
            a[0] = prow[0];
            a[1] = prow[loff0];
        }
        const uint32_t wsel = (lane == 63) ? bnd_base : (tr_base + (uint32_t)(lane * 8));
        uint32_t wcur = wsel;
        {   // initial boundary entry (chunk -1, entry 15) = slot2,e15: zeros
            const uint32_t winit = wsel + 256;
            asm volatile("ds_write2_b32 %0, %1, %2 offset0:30 offset1:31"
                         :: "v"(winit), "v"(a[3]), "v"(z2) : "memory");
        }

        auto ISSUE = [&](uint32_t slotbyte, int tbase) {
#pragma unroll
            for (int i = 0; i < 8; ++i) {
                int rowb = tbase + 2 * i;
                if (rowb > T_DIM - 2) rowb = T_DIM - 2;
                const float* src = prow + (size_t)rowb * VSTRIDE + lane;
                float* dst = &lbuf[0][0][0] + slotbyte / 4 + i * 64;
                __builtin_amdgcn_global_load_lds(
                    (const __attribute__((address_space(1))) void*)src,
                    (__attribute__((address_space(3))) void*)dst, 4, 0, 0);
            }
        };
        auto ST0 = [&](const float (&G)[3]) {
            const float s3p = shup1_f(a[3]);
            const float am1 = s3p * f;
            const float n0 = (a[0] + am1) * G[2];
            const float n1 = (a[1] + a[0] + m20 * am1) * G[0];
            const float n2 = (a[2] + a[1]) * G[2];
            const float n3 = (a[3] + a[2] + m21 * a[1]) * G[1];
            a[0] = n0; a[1] = n1; a[2] = n2; a[3] = n3;
        };
        auto REN0 = [&]() {
            const float mx = fmaxf(fmaxf(a[0], a[1]), fmaxf(a[2], a[3]));
            int e; (void)frexpf(mx, &e);
            const int zc = z2 + e;
            const int zp = shup1_i(zc);
            z2 = (mx > 0.f) ? zc : zp;
            a[0] = ldexpf(a[0], -e); a[1] = ldexpf(a[1], -e);
            a[2] = ldexpf(a[2], -e); a[3] = ldexpf(a[3], -e);
            const int dz = zp - z2;
            f = ldexpf(fz, dz);
        };

        uint32_t ro = 0, dsto = 4096;
        int tbi = 33;
        ISSUE(0, 1);
        ISSUE(2048, 17);
        VM8();
        RD3(GA, 0);
        RD3(GB, 128);

        for (int s = 0; s < F; ++s) {
            RD3(GC, 256);  WTn(8); ST0(GA);         WB(0, 1);
            RD3(GD, 384);  WTn(8); ST0(GB); REN0(); WB(2, 3);
            RD3(GA, 512);  WTn(8); ST0(GC);         WB(4, 5);
            RD3(GB, 640);  WTn(8); ST0(GD); REN0(); WB(6, 7);
            RD3(GC, 768);  WTn(8); ST0(GA);         WB(8, 9);
            RD3(GD, 896);  WTn(8); ST0(GB); REN0(); WB(10, 11);
            RD3(GA, 1024); WTn(8); ST0(GC);         WB(12, 13);
            RD3(GB, 1152); WTn(8); ST0(GD); REN0(); WB(14, 15);
            RD3(GC, 1280); WTn(8); ST0(GA);         WB(16, 17);
            RD3(GD, 1408); WTn(8); ST0(GB); REN0(); WB(18, 19);
            RD3(GA, 1536); WTn(8); ST0(GC);         WB(20, 21);
            RD3(GB, 1664); WTn(8); ST0(GD); REN0(); WB(22, 23);
            RD3(GC, 1792); WTn(8); ST0(GA);         WB(24, 25);
            RD3(GD, 1920); WTn(8); ST0(GB); REN0(); WB(26, 27);
            // advance gather ring to next slot; keep DMA pipeline full
            ro = (ro + 2048u) & 8191u;
            va[0] = lb_base + ro + (uint32_t)(loff0 * 4);
            va[1] = lb_base + ro + (uint32_t)(loff1 * 4);
            va[2] = lb_base + ro;
            ISSUE(dsto, tbi);
            dsto = (dsto + 2048u) & 8191u;
            tbi += 16;
            VM8();
            RD3(GA, 0);    WTn(8); ST0(GC);         WB(28, 29);
            RD3(GB, 128);  WTn(8); ST0(GD); REN0(); WB(30, 31);
            wcur = (wcur == wsel + 256u) ? wsel : wcur + 128u;
            BARR();
        }
        // partial superstep F: R steps (GA,GB preloaded rows 0,1 of slot F)
        if (R > 0)  { RD3(GC, 256);  WTn(8); ST0(GA);         WB(0, 1); }
        if (R > 1)  { RD3(GD, 384);  WTn(8); ST0(GB); REN0(); WB(2, 3); }
        if (R > 2)  { RD3(GA, 512);  WTn(8); ST0(GC);         WB(4, 5); }
        if (R > 3)  { RD3(GB, 640);  WTn(8); ST0(GD); REN0(); WB(6, 7); }
        if (R > 4)  { RD3(GC, 768);  WTn(8); ST0(GA);         WB(8, 9); }
        if (R > 5)  { RD3(GD, 896);  WTn(8); ST0(GB); REN0(); WB(10, 11); }
        if (R > 6)  { RD3(GA, 1024); WTn(8); ST0(GC);         WB(12, 13); }
        if (R > 7)  { RD3(GB, 1152); WTn(8); ST0(GD); REN0(); WB(14, 15); }
        if (R > 8)  { RD3(GC, 1280); WTn(8); ST0(GA);         WB(16, 17); }
        if (R > 9)  { RD3(GD, 1408); WTn(8); ST0(GB); REN0(); WB(18, 19); }
        if (R > 10) { RD3(GA, 1536); WTn(8); ST0(GC);         WB(20, 21); }
        if (R > 11) { RD3(GB, 1664); WTn(8); ST0(GD); REN0(); WB(22, 23); }
        if (R > 12) { RD3(GC, 1792); WTn(8); ST0(GA);         WB(24, 25); }
        if (R > 13) { RD3(GD, 1920); WTn(8); ST0(GB); REN0(); WB(26, 27); }
        if (R > 14) { WTn(4); ST0(GC); WB(28, 29); }
        BARR();       // final barrier (count = F+1 on both waves)
        return;
    } else {
        // ============================ WAVE 1 ============================
        const float fbz = (lane == 0) ? 1.0f : 0.f;
        f32x2 EA, EB, EC, ED;

        auto ST1 = [&](const float (&G)[3], const f32x2& E) {
            const float s3p = shup1_f(a[3]);
            float am1 = s3p * f;
            const int dzb = __float_as_int(E[1]) - z2;
            am1 = fmaf(E[0], ldexpf(fbz, dzb), am1);
            const float n0 = (a[0] + am1) * G[2];
            const float n1 = (a[1] + a[0] + m20 * am1) * G[0];
            const float n2 = (a[2] + a[1]) * G[2];
            const float n3 = (a[3] + a[2] + m21 * a[1]) * G[1];
            a[0] = n0; a[1] = n1; a[2] = n2; a[3] = n3;
        };
        auto REN1 = [&](const f32x2& E) {
            const float mx = fmaxf(fmaxf(a[0], a[1]), fmaxf(a[2], a[3]));
            int e; (void)frexpf(mx, &e);
            const int zc = z2 + e;
            int zp = shup1_i(zc);
            zp = (lane == 0) ? __float_as_int(E[1]) : zp;   // adopt across waves
            z2 = (mx > 0.f) ? zc : zp;
            a[0] = ldexpf(a[0], -e); a[1] = ldexpf(a[1], -e);
            a[2] = ldexpf(a[2], -e); a[3] = ldexpf(a[3], -e);
            const int dz = zp - z2;
            f = ldexpf(fz, dz);
        };

        uint32_t ro = 0;
        uint32_t cb = bnd_base, pb = bnd_base + 256u;
        BARR();   // superstep 0 (idle)
        for (int c = 0; c < F; ++c) {
            RD3(GA, 0);    RDE(EA, pb, 120);
            RD3(GB, 128);  RDE(EB, cb, 0);
            WTn(0);
            RD3(GC, 256);  RDE(EC, cb, 8);   WTn(8); ST1(GA, EA);
            RD3(GD, 384);  RDE(ED, cb, 16);  WTn(8); ST1(GB, EB); REN1(EB);
            RD3(GA, 512);  RDE(EA, cb, 24);  WTn(8); ST1(GC, EC);
            RD3(GB, 640);  RDE(EB, cb, 32);  WTn(8); ST1(GD, ED); REN1(ED);
            RD3(GC, 768);  RDE(EC, cb, 40);  WTn(8); ST1(GA, EA);
            RD3(GD, 896);  RDE(ED, cb, 48);  WTn(8); ST1(GB, EB); REN1(EB);
            RD3(GA, 1024); RDE(EA, cb, 56);  WTn(8); ST1(GC, EC);
            RD3(GB, 1152); RDE(EB, cb, 64);  WTn(8); ST1(GD, ED); REN1(ED);
            RD3(GC, 1280); RDE(EC, cb, 72);  WTn(8); ST1(GA, EA);
            RD3(GD, 1408); RDE(ED, cb, 80);  WTn(8); ST1(GB, EB); REN1(EB);
            RD3(GA, 1536); RDE(EA, cb, 88);  WTn(8); ST1(GC, EC);
            RD3(GB, 1664); RDE(EB, cb, 96);  WTn(8); ST1(GD, ED); REN1(ED);
            RD3(GC, 1792); RDE(EC, cb, 104); WTn(8); ST1(GA, EA);
            RD3(GD, 1920); RDE(ED, cb, 112); WTn(8); ST1(GB, EB); REN1(EB);
            WTn(4); ST1(GC, EC);
            WTn(0); ST1(GD, ED); REN1(ED);
            ro = (ro + 2048u) & 8191u;
            va[0] = lb_base + ro + (uint32_t)(loff0 * 4);
            va[1] = lb_base + ro + (uint32_t)(loff1 * 4);
            va[2] = lb_base + ro;
            pb = cb;
            cb = (cb == bnd_base + 256u) ? bnd_base : cb + 128u;
            BARR();
        }
        // free-run: chunk F (R steps); all data written before final barrier
        if (R > 0) {
            RD3(GA, 0);   RDE(EA, pb, 120);
            RD3(GB, 128); RDE(EB, cb, 0);
            WTn(0);
            RD3(GC, 256); RDE(EC, cb, 8); WTn(8); ST1(GA, EA);
        }
        if (R > 1)  { RD3(GD, 384);  RDE(ED, cb, 16);  WTn(8); ST1(GB, EB); REN1(EB); }
        if (R > 2)  { RD3(GA, 512);  RDE(EA, cb, 24);  WTn(8); ST1(GC, EC); }
        if (R > 3)  { RD3(GB, 640);  RDE(EB, cb, 32);  WTn(8); ST1(GD, ED); REN1(ED); }
        if (R > 4)  { RD3(GC, 768);  RDE(EC, cb, 40);  WTn(8); ST1(GA, EA); }
        if (R > 5)  { RD3(GD, 896);  RDE(ED, cb, 48);  WTn(8); ST1(GB, EB); REN1(EB); }
        if (R > 6)  { RD3(GA, 1024); RDE(EA, cb, 56);  WTn(8); ST1(GC, EC); }
        if (R > 7)  { RD3(GB, 1152); RDE(EB, cb, 64);  WTn(8); ST1(GD, ED); REN1(ED); }
        if (R > 8)  { RD3(GC, 1280); RDE(EC, cb, 72);  WTn(8); ST1(GA, EA); }
        if (R > 9)  { RD3(GD, 1408); RDE(ED, cb, 80);  WTn(8); ST1(GB, EB); REN1(EB); }
        if (R > 10) { RD3(GA, 1536); RDE(EA, cb, 88);  WTn(8); ST1(GC, EC); }
        if (R > 11) { RD3(GB, 1664); RDE(EB, cb, 96);  WTn(8); ST1(GD, ED); REN1(ED); }
        if (R > 12) { RD3(GC, 1792); RDE(EC, cb, 104); WTn(8); ST1(GA, EA); }
        if (R > 13) { RD3(GD, 1920); RDE(ED, cb, 112); WTn(8); ST1(GB, EB); REN1(EB); }
        if (R > 14) { WTn(4); ST1(GC, EC); }
        WTn(0);

        // absolute log-alpha for states 256..511; final states are >= 299
        const float zln2 = (float)z2 * 0.69314718055994530942f;
        sal[256 + 4 * lane + 0] = __logf(a[0]) + zln2;
        sal[256 + 4 * lane + 1] = __logf(a[1]) + zln2;
        sal[256 + 4 * lane + 2] = __logf(a[2]) + zln2;
        sal[256 + 4 * lane + 3] = __logf(a[3]) + zln2;
        asm volatile("s_waitcnt lgkmcnt(0)" ::: "memory");
        SB();
        if (lane == 0) {
            const float x0 = sal[2 * tl - 1];
            const float x1 = sal[2 * tl];
            const float m  = fmaxf(x0, x1);
            float nll = -(m + __logf(__expf(x0 - m) + __expf(x1 - m)));
            if (!(nll < 1e29f)) nll = 0.f;       // zero_infinity (inf/NaN too)
            out_nll[b] = nll / (float)tl;
        }
    }
}

// ---------------------------------------------------------------------------
// Kernel 3: deterministic mean over B
// ---------------------------------------------------------------------------
__global__ void finalize_kernel(const float* __restrict__ nll, float* __restrict__ out)
{
    if (threadIdx.x == 0 && blockIdx.x == 0) {
        float s = 0.f;
        for (int i = 0; i < B_DIM; ++i) s += nll[i];
        out[0] = s * (1.0f / (float)B_DIM);
    }
}

extern "C" void kernel_launch(void* const* d_in, const int* in_sizes, int n_in,
                              void* d_out, int out_size, void* d_ws, size_t ws_size,
                              hipStream_t stream)
{
    const float* pred     = (const float*)d_in[0];
    const int*   targets  = (const int*)d_in[1];
    const int*   in_lens  = (const int*)d_in[2];
    const int*   tgt_lens = (const int*)d_in[3];
    const float* W        = (const float*)d_in[4];
    const float* bias     = (const float*)d_in[5];

    float* probs = (float*)d_ws;                                  // 32*1000*32 f32 = 4.1 MB
    float* nll   = probs + (size_t)B_DIM * T_DIM * VSTRIDE;       // 32 f32
    float* out   = (float*)d_out;

    head_softmax_kernel<<<(B_DIM * T_DIM) / 32, 256, 0, stream>>>(pred, W, bias, probs);
    ctc_alpha_kernel<<<B_DIM, 128, 0, stream>>>(probs, targets, in_lens, tgt_lens, nll);
    finalize_kernel<<<1, 64, 0, stream>>>(nll, out);
}

// Round 17
// 94.825 us; speedup vs baseline: 1.2356x; 1.0294x over previous
//
#include <hip/hip_runtime.h>
#include <hip/hip_bf16.h>
#include <cstdint>
#include <math.h>

#define B_DIM 32
#define T_DIM 1000
#define D_DIM 768
#define V_DIM 31
#define L_DIM 200
#define S_DIM 401      // 2L+1 CTC states
#define S_PAD 512      // 2 waves x 64 lanes x 4 states
#define VSTRIDE 32     // padded prob-row stride: 32 floats = 128 B

typedef __bf16 bf16x8 __attribute__((ext_vector_type(8)));
typedef float  f32x16 __attribute__((ext_vector_type(16)));
typedef float  f32x2  __attribute__((ext_vector_type(2)));
typedef __attribute__((address_space(3))) float lds_float;

#define SB() __builtin_amdgcn_sched_barrier(0)

// Wave-wide shift-up-by-1 via DPP WAVE_SHR1 (0x138): pure VALU. Lane 0 -> 0.
__device__ __forceinline__ float shup1_f(float x) {
    int r = __builtin_amdgcn_update_dpp(0, __float_as_int(x), 0x138, 0xF, 0xF, true);
    return __int_as_float(r);
}
__device__ __forceinline__ int shup1_i(int x) {
    return __builtin_amdgcn_update_dpp(0, x, 0x138, 0xF, 0xF, true);
}

// ---------------------------------------------------------------------------
// Kernel 1: logits = pred @ W^T + b via MFMA bf16, probs = softmax -> ws.
// 2-row-tile version: 64 rows/block, each wave runs TWO MFMAs per k-tile
// sharing one B-fragment (halves B traffic/cvt, doubles A-load concurrency).
// Epilogue: stride-33 padded red[] (conflict-free scalar access), softmax
// across all 64 lanes of wave0.
// ---------------------------------------------------------------------------
__global__ __launch_bounds__(256) void head_softmax_kernel(
    const float* __restrict__ pred,
    const float* __restrict__ W,
    const float* __restrict__ bias,
    float* __restrict__ probs)
{
    __shared__ float red[3][64][33];   // waves 1..3 partials, padded (25.3 KB)
    __shared__ float sm2[64][33];      // transpose, padded (8.4 KB)
    const int tid  = threadIdx.x;
    const int lane = tid & 63;
    const int w    = __builtin_amdgcn_readfirstlane(tid >> 6);  // K segment
    const int col  = lane & 31;
    const int h    = lane >> 5;
    const int row  = blockIdx.x * 64 + col;     // grid = 500 exactly
    const int vc   = (col < V_DIM) ? col : (V_DIM - 1);  // clamp pad col

    const float* pA0 = pred + (size_t)row * D_DIM + w * 192 + 8 * h;
    const float* pA1 = pA0 + (size_t)32 * D_DIM;
    const float* pB  = W + (size_t)vc * D_DIM + w * 192 + 8 * h;

    f32x16 acc0, acc1;
#pragma unroll
    for (int i = 0; i < 16; ++i) { acc0[i] = 0.f; acc1[i] = 0.f; }

#pragma unroll
    for (int kt = 0; kt < 12; ++kt) {
        const float4 x00 = *reinterpret_cast<const float4*>(pA0 + kt * 16);
        const float4 x01 = *reinterpret_cast<const float4*>(pA0 + kt * 16 + 4);
        const float4 x10 = *reinterpret_cast<const float4*>(pA1 + kt * 16);
        const float4 x11 = *reinterpret_cast<const float4*>(pA1 + kt * 16 + 4);
        const float4 b0  = *reinterpret_cast<const float4*>(pB + kt * 16);
        const float4 b1  = *reinterpret_cast<const float4*>(pB + kt * 16 + 4);
        bf16x8 af0, af1, bfr;
        af0[0] = (__bf16)x00.x; af0[1] = (__bf16)x00.y;
        af0[2] = (__bf16)x00.z; af0[3] = (__bf16)x00.w;
        af0[4] = (__bf16)x01.x; af0[5] = (__bf16)x01.y;
        af0[6] = (__bf16)x01.z; af0[7] = (__bf16)x01.w;
        af1[0] = (__bf16)x10.x; af1[1] = (__bf16)x10.y;
        af1[2] = (__bf16)x10.z; af1[3] = (__bf16)x10.w;
        af1[4] = (__bf16)x11.x; af1[5] = (__bf16)x11.y;
        af1[6] = (__bf16)x11.z; af1[7] = (__bf16)x11.w;
        bfr[0] = (__bf16)b0.x; bfr[1] = (__bf16)b0.y;
        bfr[2] = (__bf16)b0.z; bfr[3] = (__bf16)b0.w;
        bfr[4] = (__bf16)b1.x; bfr[5] = (__bf16)b1.y;
        bfr[6] = (__bf16)b1.z; bfr[7] = (__bf16)b1.w;
        acc0 = __builtin_amdgcn_mfma_f32_32x32x16_bf16(af0, bfr, acc0, 0, 0, 0);
        acc1 = __builtin_amdgcn_mfma_f32_32x32x16_bf16(af1, bfr, acc1, 0, 0, 0);
    }

    if (w > 0) {
#pragma unroll
        for (int i = 0; i < 16; ++i) {
            red[w - 1][lane][i]      = acc0[i];
            red[w - 1][lane][16 + i] = acc1[i];
        }
    }
    __syncthreads();
    if (w == 0) {
#pragma unroll
        for (int i = 0; i < 16; ++i) {
            acc0[i] += red[0][lane][i] + red[1][lane][i] + red[2][lane][i];
            acc1[i] += red[0][lane][16 + i] + red[1][lane][16 + i] + red[2][lane][16 + i];
        }
#pragma unroll
        for (int r = 0; r < 16; ++r) {
            const int rl = (r & 3) + 8 * (r >> 2) + 4 * h;
            sm2[rl][col]      = acc0[r];
            sm2[32 + rl][col] = acc1[r];
        }
        // all 64 lanes: softmax of block-row `lane`
        float lg[V_DIM];
        float m = -1e30f;
#pragma unroll
        for (int v = 0; v < V_DIM; ++v) {
            lg[v] = sm2[lane][v] + bias[v];
            m = fmaxf(m, lg[v]);
        }
        float e[32];
        float s = 0.f;
#pragma unroll
        for (int v = 0; v < V_DIM; ++v) { e[v] = __expf(lg[v] - m); s += e[v]; }
        const float inv = 1.0f / s;
#pragma unroll
        for (int v = 0; v < V_DIM; ++v) e[v] *= inv;
        e[31] = 0.f;
        float* op = probs + (size_t)(blockIdx.x * 64 + lane) * VSTRIDE;
#pragma unroll
        for (int q = 0; q < 8; ++q)
            *reinterpret_cast<float4*>(op + q * 4) =
                *reinterpret_cast<float4*>(&e[q * 4]);
    }
}

// --- asm helpers (counted waits; rule #18: sched_barrier after lgkmcnt) ----
#define WTn(n) do { asm volatile("s_waitcnt lgkmcnt(" #n ")" ::: "memory"); SB(); } while (0)
#define VM8()  asm volatile("s_waitcnt vmcnt(8)" ::: "memory")
#define BARR() do { asm volatile("s_waitcnt lgkmcnt(0)" ::: "memory"); SB(); \
                    asm volatile("s_barrier" ::: "memory"); SB(); } while (0)
#define RD3(G, off) do { \
    asm volatile("ds_read_b32 %0, %1 offset:" #off : "=v"(G[0]) : "v"(va[0])); \
    asm volatile("ds_read_b32 %0, %1 offset:" #off : "=v"(G[1]) : "v"(va[1])); \
    asm volatile("ds_read_b32 %0, %1 offset:" #off : "=v"(G[2]) : "v"(va[2])); } while (0)
#define RDE(E, base, off) \
    asm volatile("ds_read_b64 %0, %1 offset:" #off : "=v"(E) : "v"(base))
#define WB(o0, o1) \
    asm volatile("ds_write2_b32 %0, %1, %2 offset0:" #o0 " offset1:" #o1 \
                 :: "v"(wcur), "v"(a[3]), "v"(z2) : "memory")

// ---------------------------------------------------------------------------
// Kernel 2: CTC forward recursion, linear domain, pow2 renorm every 2 steps.
// TWO waves per batch, skewed pipeline (r16 structure, verified). Decoy
// boundary writes now stride-4 (banks stride-1, conflict-free — r16's
// stride-8 caused 172K bank-conflict cycles/dispatch).
// ---------------------------------------------------------------------------
__global__ __launch_bounds__(128, 1) void ctc_alpha_kernel(
    const float* __restrict__ probs,
    const int* __restrict__ targets,
    const int* __restrict__ in_lens,
    const int* __restrict__ tgt_lens,
    float* __restrict__ out_nll)
{
    __shared__ float lbuf[4][16][VSTRIDE];          // 8 KB, slot = chunk%4
    __shared__ __align__(8) float bndb[3][16][2];   // boundary ring (a255, zbits)
    __shared__ float trash[256];                    // decoy for lane!=63 writes
    __shared__ float sal[S_PAD];

    const int b    = blockIdx.x;
    const int tid  = threadIdx.x;
    const int lane = tid & 63;
    const int w    = __builtin_amdgcn_readfirstlane(tid >> 6);
    const int Tin  = in_lens[b];
    const int tl   = tgt_lens[b];
    const int* tgt = targets + b * L_DIM;
    const float* __restrict__ prow = probs + (size_t)b * T_DIM * VSTRIDE;

    const int NS = Tin - 1;        // steps t = 1..Tin-1
    const int F  = NS >> 4;        // full chunks
    const int R  = NS & 15;        // remainder steps

    // per-lane labels (2 odd states) + skip masks; pad states inert
    int k0 = (w ? 128 : 0) + 2 * lane;
    int k1 = k0 + 1;
    if (k0 > L_DIM - 1) k0 = L_DIM - 1;
    if (k1 > L_DIM - 1) k1 = L_DIM - 1;
    const int loff0 = tgt[k0];
    const int loff1 = tgt[k1];
    const int k0m   = (k0 > 0) ? k0 - 1 : 0;
    const float m20 = (w == 0 && lane == 0) ? 0.f : ((loff0 != tgt[k0m]) ? 1.f : 0.f);
    const float m21 = (loff1 != tgt[k1 - 1]) ? 1.f : 0.f;

    const uint32_t lb_base  = (uint32_t)(uintptr_t)(lds_float*)&lbuf[0][0][0];
    const uint32_t bnd_base = (uint32_t)(uintptr_t)(lds_float*)&bndb[0][0][0];
    const uint32_t tr_base  = (uint32_t)(uintptr_t)(lds_float*)&trash[0];

    float a[4] = {0.f, 0.f, 0.f, 0.f};
    int   z2 = 0;
    const float fz = (lane == 0) ? 0.f : 1.0f;
    float f = fz;

    uint32_t va[3];
    va[0] = lb_base + (uint32_t)(loff0 * 4);
    va[1] = lb_base + (uint32_t)(loff1 * 4);
    va[2] = lb_base;

    float GA[3], GB[3], GC[3], GD[3];

    if (w == 0) {
        // ============================ WAVE 0 ============================
        if (lane == 0) {            // t=0 init: states 0,1
            a[0] = prow[0];
            a[1] = prow[loff0];
        }
        // stride-4 decoy: banks (lane+off)%32 -> stride-1, conflict-free
        const uint32_t wsel = (lane == 63) ? bnd_base : (tr_base + (uint32_t)(lane * 4));
        uint32_t wcur = wsel;
        {   // initial boundary entry (chunk -1, entry 15) = slot2,e15: zeros
            const uint32_t winit = wsel + 256;
            asm volatile("ds_write2_b32 %0, %1, %2 offset0:30 offset1:31"
                         :: "v"(winit), "v"(a[3]), "v"(z2) : "memory");
        }

        auto ISSUE = [&](uint32_t slotbyte, int tbase) {
#pragma unroll
            for (int i = 0; i < 8; ++i) {
                int rowb = tbase + 2 * i;
                if (rowb > T_DIM - 2) rowb = T_DIM - 2;
                const float* src = prow + (size_t)rowb * VSTRIDE + lane;
                float* dst = &lbuf[0][0][0] + slotbyte / 4 + i * 64;
                __builtin_amdgcn_global_load_lds(
                    (const __attribute__((address_space(1))) void*)src,
                    (__attribute__((address_space(3))) void*)dst, 4, 0, 0);
            }
        };
        auto ST0 = [&](const float (&G)[3]) {
            const float s3p = shup1_f(a[3]);
            const float am1 = s3p * f;
            const float n0 = (a[0] + am1) * G[2];
            const float n1 = (a[1] + a[0] + m20 * am1) * G[0];
            const float n2 = (a[2] + a[1]) * G[2];
            const float n3 = (a[3] + a[2] + m21 * a[1]) * G[1];
            a[0] = n0; a[1] = n1; a[2] = n2; a[3] = n3;
        };
        auto REN0 = [&]() {
            const float mx = fmaxf(fmaxf(a[0], a[1]), fmaxf(a[2], a[3]));
            int e; (void)frexpf(mx, &e);
            const int zc = z2 + e;
            const int zp = shup1_i(zc);
            z2 = (mx > 0.f) ? zc : zp;
            a[0] = ldexpf(a[0], -e); a[1] = ldexpf(a[1], -e);
            a[2] = ldexpf(a[2], -e); a[3] = ldexpf(a[3], -e);
            const int dz = zp - z2;
            f = ldexpf(fz, dz);
        };

        uint32_t ro = 0, dsto = 4096;
        int tbi = 33;
        ISSUE(0, 1);
        ISSUE(2048, 17);
        VM8();
        RD3(GA, 0);
        RD3(GB, 128);

        for (int s = 0; s < F; ++s) {
            RD3(GC, 256);  WTn(8); ST0(GA);         WB(0, 1);
            RD3(GD, 384);  WTn(8); ST0(GB); REN0(); WB(2, 3);
            RD3(GA, 512);  WTn(8); ST0(GC);         WB(4, 5);
            RD3(GB, 640);  WTn(8); ST0(GD); REN0(); WB(6, 7);
            RD3(GC, 768);  WTn(8); ST0(GA);         WB(8, 9);
            RD3(GD, 896);  WTn(8); ST0(GB); REN0(); WB(10, 11);
            RD3(GA, 1024); WTn(8); ST0(GC);         WB(12, 13);
            RD3(GB, 1152); WTn(8); ST0(GD); REN0(); WB(14, 15);
            RD3(GC, 1280); WTn(8); ST0(GA);         WB(16, 17);
            RD3(GD, 1408); WTn(8); ST0(GB); REN0(); WB(18, 19);
            RD3(GA, 1536); WTn(8); ST0(GC);         WB(20, 21);
            RD3(GB, 1664); WTn(8); ST0(GD); REN0(); WB(22, 23);
            RD3(GC, 1792); WTn(8); ST0(GA);         WB(24, 25);
            RD3(GD, 1920); WTn(8); ST0(GB); REN0(); WB(26, 27);
            // advance gather ring to next slot; keep DMA pipeline full
            ro = (ro + 2048u) & 8191u;
            va[0] = lb_base + ro + (uint32_t)(loff0 * 4);
            va[1] = lb_base + ro + (uint32_t)(loff1 * 4);
            va[2] = lb_base + ro;
            ISSUE(dsto, tbi);
            dsto = (dsto + 2048u) & 8191u;
            tbi += 16;
            VM8();
            RD3(GA, 0);    WTn(8); ST0(GC);         WB(28, 29);
            RD3(GB, 128);  WTn(8); ST0(GD); REN0(); WB(30, 31);
            wcur = (wcur == wsel + 256u) ? wsel : wcur + 128u;
            BARR();
        }
        // partial superstep F: R steps (GA,GB preloaded rows 0,1 of slot F)
        if (R > 0)  { RD3(GC, 256);  WTn(8); ST0(GA);         WB(0, 1); }
        if (R > 1)  { RD3(GD, 384);  WTn(8); ST0(GB); REN0(); WB(2, 3); }
        if (R > 2)  { RD3(GA, 512);  WTn(8); ST0(GC);         WB(4, 5); }
        if (R > 3)  { RD3(GB, 640);  WTn(8); ST0(GD); REN0(); WB(6, 7); }
        if (R > 4)  { RD3(GC, 768);  WTn(8); ST0(GA);         WB(8, 9); }
        if (R > 5)  { RD3(GD, 896);  WTn(8); ST0(GB); REN0(); WB(10, 11); }
        if (R > 6)  { RD3(GA, 1024); WTn(8); ST0(GC);         WB(12, 13); }
        if (R > 7)  { RD3(GB, 1152); WTn(8); ST0(GD); REN0(); WB(14, 15); }
        if (R > 8)  { RD3(GC, 1280); WTn(8); ST0(GA);         WB(16, 17); }
        if (R > 9)  { RD3(GD, 1408); WTn(8); ST0(GB); REN0(); WB(18, 19); }
        if (R > 10) { RD3(GA, 1536); WTn(8); ST0(GC);         WB(20, 21); }
        if (R > 11) { RD3(GB, 1664); WTn(8); ST0(GD); REN0(); WB(22, 23); }
        if (R > 12) { RD3(GC, 1792); WTn(8); ST0(GA);         WB(24, 25); }
        if (R > 13) { RD3(GD, 1920); WTn(8); ST0(GB); REN0(); WB(26, 27); }
        if (R > 14) { WTn(4); ST0(GC); WB(28, 29); }
        BARR();       // final barrier (count = F+1 on both waves)
        return;
    } else {
        // ============================ WAVE 1 ============================
        const float fbz = (lane == 0) ? 1.0f : 0.f;
        f32x2 EA, EB, EC, ED;

        auto ST1 = [&](const float (&G)[3], const f32x2& E) {
            const float s3p = shup1_f(a[3]);
            float am1 = s3p * f;
            const int dzb = __float_as_int(E[1]) - z2;
            am1 = fmaf(E[0], ldexpf(fbz, dzb), am1);
            const float n0 = (a[0] + am1) * G[2];
            const float n1 = (a[1] + a[0] + m20 * am1) * G[0];
            const float n2 = (a[2] + a[1]) * G[2];
            const float n3 = (a[3] + a[2] + m21 * a[1]) * G[1];
            a[0] = n0; a[1] = n1; a[2] = n2; a[3] = n3;
        };
        auto REN1 = [&](const f32x2& E) {
            const float mx = fmaxf(fmaxf(a[0], a[1]), fmaxf(a[2], a[3]));
            int e; (void)frexpf(mx, &e);
            const int zc = z2 + e;
            int zp = shup1_i(zc);
            zp = (lane == 0) ? __float_as_int(E[1]) : zp;   // adopt across waves
            z2 = (mx > 0.f) ? zc : zp;
            a[0] = ldexpf(a[0], -e); a[1] = ldexpf(a[1], -e);
            a[2] = ldexpf(a[2], -e); a[3] = ldexpf(a[3], -e);
            const int dz = zp - z2;
            f = ldexpf(fz, dz);
        };

        uint32_t ro = 0;
        uint32_t cb = bnd_base, pb = bnd_base + 256u;
        BARR();   // superstep 0 (idle)
        for (int c = 0; c < F; ++c) {
            RD3(GA, 0);    RDE(EA, pb, 120);
            RD3(GB, 128);  RDE(EB, cb, 0);
            WTn(0);
            RD3(GC, 256);  RDE(EC, cb, 8);   WTn(8); ST1(GA, EA);
            RD3(GD, 384);  RDE(ED, cb, 16);  WTn(8); ST1(GB, EB); REN1(EB);
            RD3(GA, 512);  RDE(EA, cb, 24);  WTn(8); ST1(GC, EC);
            RD3(GB, 640);  RDE(EB, cb, 32);  WTn(8); ST1(GD, ED); REN1(ED);
            RD3(GC, 768);  RDE(EC, cb, 40);  WTn(8); ST1(GA, EA);
            RD3(GD, 896);  RDE(ED, cb, 48);  WTn(8); ST1(GB, EB); REN1(EB);
            RD3(GA, 1024); RDE(EA, cb, 56);  WTn(8); ST1(GC, EC);
            RD3(GB, 1152); RDE(EB, cb, 64);  WTn(8); ST1(GD, ED); REN1(ED);
            RD3(GC, 1280); RDE(EC, cb, 72);  WTn(8); ST1(GA, EA);
            RD3(GD, 1408); RDE(ED, cb, 80);  WTn(8); ST1(GB, EB); REN1(EB);
            RD3(GA, 1536); RDE(EA, cb, 88);  WTn(8); ST1(GC, EC);
            RD3(GB, 1664); RDE(EB, cb, 96);  WTn(8); ST1(GD, ED); REN1(ED);
            RD3(GC, 1792); RDE(EC, cb, 104); WTn(8); ST1(GA, EA);
            RD3(GD, 1920); RDE(ED, cb, 112); WTn(8); ST1(GB, EB); REN1(EB);
            WTn(4); ST1(GC, EC);
            WTn(0); ST1(GD, ED); REN1(ED);
            ro = (ro + 2048u) & 8191u;
            va[0] = lb_base + ro + (uint32_t)(loff0 * 4);
            va[1] = lb_base + ro + (uint32_t)(loff1 * 4);
            va[2] = lb_base + ro;
            pb = cb;
            cb = (cb == bnd_base + 256u) ? bnd_base : cb + 128u;
            BARR();
        }
        // free-run: chunk F (R steps); all data written before final barrier
        if (R > 0) {
            RD3(GA, 0);   RDE(EA, pb, 120);
            RD3(GB, 128); RDE(EB, cb, 0);
            WTn(0);
            RD3(GC, 256); RDE(EC, cb, 8); WTn(8); ST1(GA, EA);
        }
        if (R > 1)  { RD3(GD, 384);  RDE(ED, cb, 16);  WTn(8); ST1(GB, EB); REN1(EB); }
        if (R > 2)  { RD3(GA, 512);  RDE(EA, cb, 24);  WTn(8); ST1(GC, EC); }
        if (R > 3)  { RD3(GB, 640);  RDE(EB, cb, 32);  WTn(8); ST1(GD, ED); REN1(ED); }
        if (R > 4)  { RD3(GC, 768);  RDE(EC, cb, 40);  WTn(8); ST1(GA, EA); }
        if (R > 5)  { RD3(GD, 896);  RDE(ED, cb, 48);  WTn(8); ST1(GB, EB); REN1(EB); }
        if (R > 6)  { RD3(GA, 1024); RDE(EA, cb, 56);  WTn(8); ST1(GC, EC); }
        if (R > 7)  { RD3(GB, 1152); RDE(EB, cb, 64);  WTn(8); ST1(GD, ED); REN1(ED); }
        if (R > 8)  { RD3(GC, 1280); RDE(EC, cb, 72);  WTn(8); ST1(GA, EA); }
        if (R > 9)  { RD3(GD, 1408); RDE(ED, cb, 80);  WTn(8); ST1(GB, EB); REN1(EB); }
        if (R > 10) { RD3(GA, 1536); RDE(EA, cb, 88);  WTn(8); ST1(GC, EC); }
        if (R > 11) { RD3(GB, 1664); RDE(EB, cb, 96);  WTn(8); ST1(GD, ED); REN1(ED); }
        if (R > 12) { RD3(GC, 1792); RDE(EC, cb, 104); WTn(8); ST1(GA, EA); }
        if (R > 13) { RD3(GD, 1920); RDE(ED, cb, 112); WTn(8); ST1(GB, EB); REN1(EB); }
        if (R > 14) { WTn(4); ST1(GC, EC); }
        WTn(0);

        // absolute log-alpha for states 256..511; final states are >= 299
        const float zln2 = (float)z2 * 0.69314718055994530942f;
        sal[256 + 4 * lane + 0] = __logf(a[0]) + zln2;
        sal[256 + 4 * lane + 1] = __logf(a[1]) + zln2;
        sal[256 + 4 * lane + 2] = __logf(a[2]) + zln2;
        sal[256 + 4 * lane + 3] = __logf(a[3]) + zln2;
        asm volatile("s_waitcnt lgkmcnt(0)" ::: "memory");
        SB();
        if (lane == 0) {
            const float x0 = sal[2 * tl - 1];
            const float x1 = sal[2 * tl];
            const float m  = fmaxf(x0, x1);
            float nll = -(m + __logf(__expf(x0 - m) + __expf(x1 - m)));
            if (!(nll < 1e29f)) nll = 0.f;       // zero_infinity (inf/NaN too)
            out_nll[b] = nll / (float)tl;
        }
    }
}

// ---------------------------------------------------------------------------
// Kernel 3: deterministic mean over B
// ---------------------------------------------------------------------------
__global__ void finalize_kernel(const float* __restrict__ nll, float* __restrict__ out)
{
    if (threadIdx.x == 0 && blockIdx.x == 0) {
        float s = 0.f;
        for (int i = 0; i < B_DIM; ++i) s += nll[i];
        out[0] = s * (1.0f / (float)B_DIM);
    }
}

extern "C" void kernel_launch(void* const* d_in, const int* in_sizes, int n_in,
                              void* d_out, int out_size, void* d_ws, size_t ws_size,
                              hipStream_t stream)
{
    const float* pred     = (const float*)d_in[0];
    const int*   targets  = (const int*)d_in[1];
    const int*   in_lens  = (const int*)d_in[2];
    const int*   tgt_lens = (const int*)d_in[3];
    const float* W        = (const float*)d_in[4];
    const float* bias     = (const float*)d_in[5];

    float* probs = (float*)d_ws;                                  // 32*1000*32 f32 = 4.1 MB
    float* nll   = probs + (size_t)B_DIM * T_DIM * VSTRIDE;       // 32 f32
    float* out   = (float*)d_out;

    head_softmax_kernel<<<(B_DIM * T_DIM) / 64, 256, 0, stream>>>(pred, W, bias, probs);
    ctc_alpha_kernel<<<B_DIM, 128, 0, stream>>>(probs, targets, in_lens, tgt_lens, nll);
    finalize_kernel<<<1, 64, 0, stream>>>(nll, out);
}